// Round 1
// baseline (576.027 us; speedup 1.0000x reference)
//
#include <hip/hip_runtime.h>
#include <math.h>

#define N_NODES 50000
#define N_EDGES 800000
#define IN_DIM  256
#define F1      128   // HEADS*HID
#define HEADS   4
#define OUT_DIM 40
#define NEG     0.2f

// ---------------- CSR build (by destination) ----------------
__global__ void hist_kernel(const int* __restrict__ ei, int* __restrict__ cnt) {
  int i = blockIdx.x * blockDim.x + threadIdx.x;
  if (i < N_EDGES) atomicAdd(&cnt[ei[N_EDGES + i]], 1);
}

__global__ __launch_bounds__(1024) void scan_kernel(const int* __restrict__ cnt,
                                                    int* __restrict__ row_ptr,
                                                    int* __restrict__ cursor) {
  __shared__ int lds[1024];
  __shared__ int carry_s;
  int tid = threadIdx.x;
  if (tid == 0) carry_s = 0;
  __syncthreads();
  for (int base = 0; base < N_NODES; base += 1024) {
    int i = base + tid;
    int v = (i < N_NODES) ? cnt[i] : 0;
    int c = carry_s;
    lds[tid] = v;
    __syncthreads();
    for (int off = 1; off < 1024; off <<= 1) {
      int t = (tid >= off) ? lds[tid - off] : 0;
      __syncthreads();
      lds[tid] += t;
      __syncthreads();
    }
    int excl = c + lds[tid] - v;
    if (i < N_NODES) { row_ptr[i] = excl; cursor[i] = excl; }
    __syncthreads();
    if (tid == 1023) carry_s = c + lds[1023];
    __syncthreads();
  }
  if (tid == 0) row_ptr[N_NODES] = carry_s;
}

__global__ void scatter_kernel(const int* __restrict__ ei, int* __restrict__ cursor,
                               int* __restrict__ col) {
  int i = blockIdx.x * blockDim.x + threadIdx.x;
  if (i < N_EDGES) {
    int p = atomicAdd(&cursor[ei[N_EDGES + i]], 1);
    col[p] = ei[i];
  }
}

// ---------------- GEMM1: h1 = x @ W1  [50000,256]x[256,128] ----------------
#define BM 64
#define BN 64
#define BK 32

__global__ __launch_bounds__(256) void gemm1_kernel(
    const float* __restrict__ A, const float* __restrict__ B, float* __restrict__ C) {
  __shared__ float As[BK][BM + 4];   // +4 pad: bank-spread, keeps 16B alignment
  __shared__ float Bs[BK][BN + 4];
  int tid = threadIdx.x;
  int bm = blockIdx.x * BM;
  int bn = blockIdx.y * BN;
  int tx = tid & 15;
  int ty = tid >> 4;
  float acc[4][4] = {{0.f}};
  for (int k0 = 0; k0 < IN_DIM; k0 += BK) {
#pragma unroll
    for (int l = 0; l < 2; l++) {
      int idx = tid + l * 256;
      int r = idx >> 3;
      int c4 = (idx & 7) << 2;
      int grow = bm + r;
      float4 v = make_float4(0.f, 0.f, 0.f, 0.f);
      if (grow < N_NODES) v = *(const float4*)&A[(size_t)grow * IN_DIM + k0 + c4];
      As[c4 + 0][r] = v.x;
      As[c4 + 1][r] = v.y;
      As[c4 + 2][r] = v.z;
      As[c4 + 3][r] = v.w;
    }
#pragma unroll
    for (int l = 0; l < 2; l++) {
      int idx = tid + l * 256;
      int r = idx >> 4;
      int c4 = (idx & 15) << 2;
      *(float4*)&Bs[r][c4] = *(const float4*)&B[(size_t)(k0 + r) * F1 + bn + c4];
    }
    __syncthreads();
#pragma unroll
    for (int kk = 0; kk < BK; kk++) {
      float a[4], b[4];
      *(float4*)a = *(const float4*)&As[kk][ty * 4];
      *(float4*)b = *(const float4*)&Bs[kk][tx * 4];
#pragma unroll
      for (int i = 0; i < 4; i++)
#pragma unroll
        for (int j = 0; j < 4; j++)
          acc[i][j] += a[i] * b[j];
    }
    __syncthreads();
  }
#pragma unroll
  for (int i = 0; i < 4; i++) {
    int grow = bm + ty * 4 + i;
    if (grow < N_NODES) {
      float4 v = make_float4(acc[i][0], acc[i][1], acc[i][2], acc[i][3]);
      *(float4*)&C[(size_t)grow * F1 + bn + tx * 4] = v;
    }
  }
}

// ---------------- alpha1: per-(node,head) dot products ----------------
__global__ __launch_bounds__(256) void alpha1_kernel(
    const float* __restrict__ h1, const float* __restrict__ a_src,
    const float* __restrict__ a_dst, float* __restrict__ as1, float* __restrict__ ad1) {
  int t = blockIdx.x * blockDim.x + threadIdx.x;   // t = n*HEADS + h
  if (t >= N_NODES * HEADS) return;
  int h = t & (HEADS - 1);
  const float4* hp = (const float4*)(h1 + (size_t)t * 32);
  const float4* ap = (const float4*)(a_src + h * 32);
  const float4* dp = (const float4*)(a_dst + h * 32);
  float sa = 0.f, sd = 0.f;
#pragma unroll
  for (int j = 0; j < 8; j++) {
    float4 v = hp[j], a = ap[j], d = dp[j];
    sa += v.x * a.x + v.y * a.y + v.z * a.z + v.w * a.w;
    sd += v.x * d.x + v.y * d.y + v.z * d.z + v.w * d.w;
  }
  as1[t] = sa;
  ad1[t] = sd;
}

// ---------------- aggregate layer 1 (block = 128 thr = 1 node) ----------------
__global__ __launch_bounds__(128) void aggregate1_kernel(
    const float* __restrict__ h1, const float* __restrict__ as1,
    const float* __restrict__ ad1, const float* __restrict__ b1,
    const int* __restrict__ row_ptr, const int* __restrict__ col,
    float* __restrict__ x2) {
  int n = blockIdx.x;
  int tid = threadIdx.x;
  int start = row_ptr[n];
  int deg = row_ptr[n + 1] - start;        // self-loop handled as virtual edge deg
  __shared__ float msh[HEADS], ssh[HEADS];
  if (tid < 64) {
    float m[HEADS], s[HEADS], adh[HEADS];
#pragma unroll
    for (int h = 0; h < HEADS; h++) { m[h] = -1e30f; s[h] = 0.f; adh[h] = ad1[n * HEADS + h]; }
    for (int i = tid; i < deg + 1; i += 64) {
      int src = (i < deg) ? col[start + i] : n;
#pragma unroll
      for (int h = 0; h < HEADS; h++) {
        float e = as1[src * HEADS + h] + adh[h];
        e = e > 0.f ? e : e * NEG;
        float mn = fmaxf(m[h], e);
        s[h] = s[h] * __expf(m[h] - mn) + __expf(e - mn);
        m[h] = mn;
      }
    }
#pragma unroll
    for (int off = 32; off > 0; off >>= 1) {
#pragma unroll
      for (int h = 0; h < HEADS; h++) {
        float m2 = __shfl_xor(m[h], off);
        float s2 = __shfl_xor(s[h], off);
        float mn = fmaxf(m[h], m2);
        s[h] = s[h] * __expf(m[h] - mn) + s2 * __expf(m2 - mn);
        m[h] = mn;
      }
    }
    if (tid == 0) {
#pragma unroll
      for (int h = 0; h < HEADS; h++) { msh[h] = m[h]; ssh[h] = s[h]; }
    }
  }
  __syncthreads();
  int h = tid >> 5;
  float mh = msh[h];
  float inv = 1.f / (ssh[h] + 1e-16f);
  float adh = ad1[n * HEADS + h];
  float acc = 0.f;
  for (int i = 0; i <= deg; i++) {
    int src = (i < deg) ? col[start + i] : n;
    float e = as1[src * HEADS + h] + adh;
    e = e > 0.f ? e : e * NEG;
    float w = __expf(e - mh);
    acc += w * h1[(size_t)src * F1 + tid];
  }
  float o = acc * inv + b1[tid];
  x2[(size_t)n * F1 + tid] = fmaxf(o, 0.f);   // ReLU between layers
}

// ---------------- GEMM2 + alpha2 fused (wave per row) ----------------
__global__ __launch_bounds__(64) void gemm2_kernel(
    const float* __restrict__ x2, const float* __restrict__ W2,
    const float* __restrict__ asv, const float* __restrict__ adv,
    float* __restrict__ h2, float* __restrict__ as2, float* __restrict__ ad2) {
  int n = blockIdx.x;
  int tid = threadIdx.x;
  __shared__ float xs[F1];
  xs[tid] = x2[(size_t)n * F1 + tid];
  xs[tid + 64] = x2[(size_t)n * F1 + 64 + tid];
  __syncthreads();
  float acc = 0.f;
  if (tid < OUT_DIM) {
#pragma unroll 8
    for (int k = 0; k < F1; k++) acc += xs[k] * W2[k * OUT_DIM + tid];
  }
  float pa = (tid < OUT_DIM) ? acc * asv[tid] : 0.f;
  float pd = (tid < OUT_DIM) ? acc * adv[tid] : 0.f;
#pragma unroll
  for (int off = 32; off > 0; off >>= 1) {
    pa += __shfl_xor(pa, off);
    pd += __shfl_xor(pd, off);
  }
  if (tid < OUT_DIM) h2[(size_t)n * OUT_DIM + tid] = acc;
  if (tid == 0) { as2[n] = pa; ad2[n] = pd; }
}

// ---------------- aggregate layer 2 + log_softmax (wave per node) ----------------
__global__ __launch_bounds__(64) void aggregate2_kernel(
    const float* __restrict__ h2, const float* __restrict__ as2,
    const float* __restrict__ ad2, const float* __restrict__ b2,
    const int* __restrict__ row_ptr, const int* __restrict__ col,
    float* __restrict__ out) {
  int n = blockIdx.x;
  int tid = threadIdx.x;
  int start = row_ptr[n];
  int deg = row_ptr[n + 1] - start;
  float adh = ad2[n];
  float m = -1e30f, s = 0.f;
  for (int i = tid; i < deg + 1; i += 64) {
    int src = (i < deg) ? col[start + i] : n;
    float e = as2[src] + adh;
    e = e > 0.f ? e : e * NEG;
    float mn = fmaxf(m, e);
    s = s * __expf(m - mn) + __expf(e - mn);
    m = mn;
  }
#pragma unroll
  for (int off = 32; off > 0; off >>= 1) {
    float m2 = __shfl_xor(m, off);
    float s2 = __shfl_xor(s, off);
    float mn = fmaxf(m, m2);
    s = s * __expf(m - mn) + s2 * __expf(m2 - mn);
    m = mn;
  }
  float inv = 1.f / (s + 1e-16f);
  float acc = 0.f;
  for (int i = 0; i <= deg; i++) {
    int src = (i < deg) ? col[start + i] : n;
    float e = as2[src] + adh;
    e = e > 0.f ? e : e * NEG;
    float w = __expf(e - m);
    if (tid < OUT_DIM) acc += w * h2[(size_t)src * OUT_DIM + tid];
  }
  float val = (tid < OUT_DIM) ? (acc * inv + b2[tid]) : -1e30f;
  // log_softmax over the 40 channels (lanes >= 40 contribute identity)
  float mx = val;
#pragma unroll
  for (int off = 32; off > 0; off >>= 1) mx = fmaxf(mx, __shfl_xor(mx, off));
  float ex = (tid < OUT_DIM) ? __expf(val - mx) : 0.f;
  float sum = ex;
#pragma unroll
  for (int off = 32; off > 0; off >>= 1) sum += __shfl_xor(sum, off);
  if (tid < OUT_DIM) out[(size_t)n * OUT_DIM + tid] = val - mx - __logf(sum);
}

extern "C" void kernel_launch(void* const* d_in, const int* in_sizes, int n_in,
                              void* d_out, int out_size, void* d_ws, size_t ws_size,
                              hipStream_t stream) {
  const float* x      = (const float*)d_in[0];
  const int*   ei     = (const int*)d_in[1];   // [2, E]: src row then dst row
  const float* W1     = (const float*)d_in[2];
  const float* a_src1 = (const float*)d_in[3];
  const float* a_dst1 = (const float*)d_in[4];
  const float* b1     = (const float*)d_in[5];
  const float* W2     = (const float*)d_in[6];
  const float* a_src2 = (const float*)d_in[7];
  const float* a_dst2 = (const float*)d_in[8];
  const float* b2     = (const float*)d_in[9];
  float* out = (float*)d_out;

  char* ws = (char*)d_ws;
  size_t off = 0;
  auto alloc = [&](size_t bytes) -> void* {
    void* p = ws + off;
    off += (bytes + 255) & ~(size_t)255;
    return p;
  };
  float* h1  = (float*)alloc((size_t)N_NODES * F1 * 4);        // 25.6 MB
  float* as1 = (float*)alloc((size_t)N_NODES * HEADS * 4);
  float* ad1 = (float*)alloc((size_t)N_NODES * HEADS * 4);
  float* x2  = (float*)alloc((size_t)N_NODES * F1 * 4);        // 25.6 MB
  float* h2  = (float*)alloc((size_t)N_NODES * OUT_DIM * 4);   // 8 MB
  float* as2 = (float*)alloc((size_t)N_NODES * 4);
  float* ad2 = (float*)alloc((size_t)N_NODES * 4);
  int* row_ptr = (int*)alloc((size_t)(N_NODES + 1) * 4);
  int* cursor  = (int*)alloc((size_t)N_NODES * 4);
  int* cnt     = (int*)alloc((size_t)N_NODES * 4);
  int* col     = (int*)alloc((size_t)N_EDGES * 4);             // 3.2 MB

  hipMemsetAsync(cnt, 0, (size_t)N_NODES * 4, stream);
  hist_kernel<<<(N_EDGES + 255) / 256, 256, 0, stream>>>(ei, cnt);
  scan_kernel<<<1, 1024, 0, stream>>>(cnt, row_ptr, cursor);
  scatter_kernel<<<(N_EDGES + 255) / 256, 256, 0, stream>>>(ei, cursor, col);

  gemm1_kernel<<<dim3((N_NODES + BM - 1) / BM, F1 / BN), 256, 0, stream>>>(x, W1, h1);
  alpha1_kernel<<<(N_NODES * HEADS + 255) / 256, 256, 0, stream>>>(h1, a_src1, a_dst1, as1, ad1);
  aggregate1_kernel<<<N_NODES, 128, 0, stream>>>(h1, as1, ad1, b1, row_ptr, col, x2);
  gemm2_kernel<<<N_NODES, 64, 0, stream>>>(x2, W2, a_src2, a_dst2, h2, as2, ad2);
  aggregate2_kernel<<<N_NODES, 64, 0, stream>>>(h2, as2, ad2, b2, row_ptr, col, out);
}